// Round 3
// baseline (1493.644 us; speedup 1.0000x reference)
//
#include <hip/hip_runtime.h>
#include <hip/hip_bf16.h>

#define NN 100000
#define NE 1600000
#define DD 128

// ---------------------------------------------------------------------------
// Detect whether edge_index arrived as int64 (little-endian: odd int32 words
// all zero) or int32. flag[0] = 1 if int64, 0 if int32.
__global__ __launch_bounds__(256) void detect_kernel(const int* __restrict__ ei,
                                                     int* __restrict__ flag) {
    __shared__ int red[256];
    int t = threadIdx.x;
    int v = 0;
    for (int i = t; i < 4096; i += 256) v |= ei[2 * i + 1];
    red[t] = v;
    __syncthreads();
    for (int s = 128; s > 0; s >>= 1) {
        if (t < s) red[t] |= red[t + s];
        __syncthreads();
    }
    if (t == 0) flag[0] = (red[0] == 0) ? 1 : 0;
}

__device__ __forceinline__ int eidx(const int* __restrict__ ei, int idx, int is64) {
    return is64 ? ei[2 * idx] : ei[idx];
}

// ---------------------------------------------------------------------------
// CSR build: degree count -> exclusive scan -> cursor init -> fill
__global__ __launch_bounds__(256) void count_deg(const int* __restrict__ ei,
                                                 const int* __restrict__ flag,
                                                 int* __restrict__ deg) {
    int e = blockIdx.x * 256 + threadIdx.x;
    if (e < NE) {
        int is64 = flag[0];
        int dst = eidx(ei, NE + e, is64);
        atomicAdd(&deg[dst], 1);
    }
}

// Single-block exclusive scan over NN degrees (wave shuffle scan, few barriers)
__global__ __launch_bounds__(1024) void scan_excl(const int* __restrict__ deg,
                                                  int* __restrict__ ptr) {
    __shared__ int wsum[16];
    __shared__ int carry_s;
    int t = threadIdx.x;
    int lane = t & 63, w = t >> 6;
    if (t == 0) carry_s = 0;
    __syncthreads();
    for (int base = 0; base < NN; base += 1024) {
        int i = base + t;
        int v = (i < NN) ? deg[i] : 0;
        int x = v;
        #pragma unroll
        for (int off = 1; off < 64; off <<= 1) {
            int y = __shfl_up(x, off, 64);
            if (lane >= off) x += y;
        }
        if (lane == 63) wsum[w] = x;
        __syncthreads();
        if (w == 0) {
            int s = (lane < 16) ? wsum[lane] : 0;
            #pragma unroll
            for (int off = 1; off < 16; off <<= 1) {
                int y = __shfl_up(s, off, 64);
                if (lane >= off) s += y;
            }
            if (lane < 16) wsum[lane] = s;  // inclusive wave-sum scan
        }
        __syncthreads();
        int carry = carry_s;
        int woff = (w == 0) ? 0 : wsum[w - 1];
        if (i < NN) ptr[i] = carry + woff + (x - v);
        int chunk_total = wsum[15];
        __syncthreads();
        if (t == 0) carry_s = carry + chunk_total;
        __syncthreads();
    }
    if (threadIdx.x == 0) ptr[NN] = carry_s;
}

__global__ __launch_bounds__(256) void init_aux(const int* __restrict__ deg,
                                                const int* __restrict__ ptr,
                                                float* __restrict__ invd,
                                                int* __restrict__ cursor) {
    int i = blockIdx.x * 256 + threadIdx.x;
    if (i < NN) {
        int d = deg[i];
        invd[i] = 1.0f / (float)(d > 1 ? d : 1);
        cursor[i] = ptr[i];
    }
}

__global__ __launch_bounds__(256) void fill_csr(const int* __restrict__ ei,
                                                const int* __restrict__ flag,
                                                int* __restrict__ cursor,
                                                int* __restrict__ csre) {
    int e = blockIdx.x * 256 + threadIdx.x;
    if (e < NE) {
        int is64 = flag[0];
        int dst = eidx(ei, NE + e, is64);
        int src = eidx(ei, e, is64);
        int pos = atomicAdd(&cursor[dst], 1);
        csre[pos] = src;
    }
}

// ---------------------------------------------------------------------------
// Mean aggregation: one wave per node, float2 per lane (64*8B = 512B per row).
// Accumulate in registers, multiply by 1/max(deg,1) at the end. No atomics.
__global__ __launch_bounds__(256) void aggregate(const float* __restrict__ h,
                                                 const int* __restrict__ csre,
                                                 const int* __restrict__ ptr,
                                                 const float* __restrict__ invd,
                                                 float* __restrict__ agg) {
    int gw = blockIdx.x * 4 + (threadIdx.x >> 6);
    int lane = threadIdx.x & 63;
    if (gw >= NN) return;
    int beg = ptr[gw], end = ptr[gw + 1];
    float ax = 0.f, ay = 0.f;
    for (int j = beg; j < end; ++j) {
        int src = csre[j];
        float2 v = *(const float2*)(h + (size_t)src * DD + lane * 2);
        ax += v.x;
        ay += v.y;
    }
    float s = invd[gw];
    float2 o;
    o.x = ax * s;
    o.y = ay * s;
    *(float2*)(agg + (size_t)gw * DD + lane * 2) = o;
}

// ---------------------------------------------------------------------------
// Fused GEMM: out[64rows x 128cols] = [agg | h] @ [Wl ; Wr] + bl (, relu)
// Virtual K = 256 (k<128 from agg/Wl, k>=128 from h/Wr).
// 256 threads: c = t&31 -> cols c*4..c*4+3 ; r = t>>5 -> rows r+8i, i=0..7.
__global__ __launch_bounds__(256) void gemm_fused(const float* __restrict__ A0,
                                                  const float* __restrict__ A1,
                                                  const float* __restrict__ W0,
                                                  const float* __restrict__ W1,
                                                  const float* __restrict__ bias,
                                                  float* __restrict__ out,
                                                  int relu) {
    __shared__ float As[64][32];
    __shared__ float Ws[32][128];
    int t = threadIdx.x;
    int row0 = blockIdx.x * 64;
    int c = t & 31;
    int r = t >> 5;
    float acc[8][4];
    #pragma unroll
    for (int i = 0; i < 8; ++i) {
        acc[i][0] = 0.f; acc[i][1] = 0.f; acc[i][2] = 0.f; acc[i][3] = 0.f;
    }

    for (int kt = 0; kt < 8; ++kt) {
        // --- stage A tile: 64 rows x 32 k (512 float4s, 2 per thread)
        const float* Asrc = (kt < 4) ? A0 : A1;
        int kbase = (kt & 3) * 32;
        #pragma unroll
        for (int i = 0; i < 2; ++i) {
            int fidx = t + 256 * i;
            int arow = fidx >> 3;
            int af = fidx & 7;
            int gr = row0 + arow;
            float4 v = make_float4(0.f, 0.f, 0.f, 0.f);
            if (gr < NN) v = *(const float4*)(Asrc + (size_t)gr * DD + kbase + af * 4);
            *(float4*)(&As[arow][af * 4]) = v;
        }
        // --- stage W tile: 32 k-rows x 128 cols (1024 float4s, 4 per thread)
        const float* Wsrc = (kt < 4) ? W0 : W1;
        int wrbase = (kt & 3) * 32;
        #pragma unroll
        for (int i = 0; i < 4; ++i) {
            int fidx = t + 256 * i;
            int wr_ = fidx >> 5;
            int wc = fidx & 31;
            float4 v = *(const float4*)(Wsrc + (size_t)(wrbase + wr_) * DD + wc * 4);
            *(float4*)(&Ws[wr_][wc * 4]) = v;
        }
        __syncthreads();
        // --- FMA loop: 8 k-groups of 4
        #pragma unroll
        for (int kk4 = 0; kk4 < 8; ++kk4) {
            float4 wv0 = *(const float4*)(&Ws[kk4 * 4 + 0][c * 4]);
            float4 wv1 = *(const float4*)(&Ws[kk4 * 4 + 1][c * 4]);
            float4 wv2 = *(const float4*)(&Ws[kk4 * 4 + 2][c * 4]);
            float4 wv3 = *(const float4*)(&Ws[kk4 * 4 + 3][c * 4]);
            #pragma unroll
            for (int i = 0; i < 8; ++i) {
                float4 av = *(const float4*)(&As[r + 8 * i][kk4 * 4]);
                acc[i][0] += av.x * wv0.x + av.y * wv1.x + av.z * wv2.x + av.w * wv3.x;
                acc[i][1] += av.x * wv0.y + av.y * wv1.y + av.z * wv2.y + av.w * wv3.y;
                acc[i][2] += av.x * wv0.z + av.y * wv1.z + av.z * wv2.z + av.w * wv3.z;
                acc[i][3] += av.x * wv0.w + av.y * wv1.w + av.z * wv2.w + av.w * wv3.w;
            }
        }
        __syncthreads();
    }

    float4 b = *(const float4*)(bias + c * 4);
    #pragma unroll
    for (int i = 0; i < 8; ++i) {
        int gr = row0 + r + 8 * i;
        if (gr < NN) {
            float4 o;
            o.x = acc[i][0] + b.x;
            o.y = acc[i][1] + b.y;
            o.z = acc[i][2] + b.z;
            o.w = acc[i][3] + b.w;
            if (relu) {
                o.x = fmaxf(o.x, 0.f); o.y = fmaxf(o.y, 0.f);
                o.z = fmaxf(o.z, 0.f); o.w = fmaxf(o.w, 0.f);
            }
            *(float4*)(out + (size_t)gr * DD + c * 4) = o;
        }
    }
}

// ---------------------------------------------------------------------------
extern "C" void kernel_launch(void* const* d_in, const int* in_sizes, int n_in,
                              void* d_out, int out_size, void* d_ws, size_t ws_size,
                              hipStream_t stream) {
    const float* x   = (const float*)d_in[0];
    const int*   ei  = (const int*)d_in[1];
    const float* Wl0 = (const float*)d_in[2];
    const float* bl0 = (const float*)d_in[3];
    const float* Wr0 = (const float*)d_in[4];
    const float* Wl1 = (const float*)d_in[5];
    const float* bl1 = (const float*)d_in[6];
    const float* Wr1 = (const float*)d_in[7];
    const float* Wl2 = (const float*)d_in[8];
    const float* bl2 = (const float*)d_in[9];
    const float* Wr2 = (const float*)d_in[10];
    float* out = (float*)d_out;

    char* p = (char*)d_ws;
    auto alloc = [&](size_t bytes) {
        char* q = p;
        p += (bytes + 255) & ~(size_t)255;
        return q;
    };
    int*   deg    = (int*)alloc((size_t)NN * 4);
    int*   ptr    = (int*)alloc((size_t)(NN + 1) * 4);
    int*   cursor = (int*)alloc((size_t)NN * 4);
    int*   csre   = (int*)alloc((size_t)NE * 4);
    float* invd   = (float*)alloc((size_t)NN * 4);
    int*   flag   = (int*)alloc(256);
    float* agg    = (float*)alloc((size_t)NN * DD * 4);
    float* h1     = (float*)alloc((size_t)NN * DD * 4);

    // ---- CSR build (edge structure identical for all 3 layers)
    hipMemsetAsync(deg, 0, (size_t)NN * 4, stream);
    detect_kernel<<<1, 256, 0, stream>>>(ei, flag);
    count_deg<<<(NE + 255) / 256, 256, 0, stream>>>(ei, flag, deg);
    scan_excl<<<1, 1024, 0, stream>>>(deg, ptr);
    init_aux<<<(NN + 255) / 256, 256, 0, stream>>>(deg, ptr, invd, cursor);
    fill_csr<<<(NE + 255) / 256, 256, 0, stream>>>(ei, flag, cursor, csre);

    dim3 blk(256);
    dim3 gAgg(NN / 4);            // 4 nodes (waves) per block
    dim3 gGemm((NN + 63) / 64);   // 64 rows per block

    // ---- layer 0: x -> h1 (relu)
    aggregate<<<gAgg, blk, 0, stream>>>(x, csre, ptr, invd, agg);
    gemm_fused<<<gGemm, blk, 0, stream>>>(agg, x, Wl0, Wr0, bl0, h1, 1);
    // ---- layer 1: h1 -> d_out (relu)   (h2 aliased onto d_out; safe:
    //      gemm blocks read/write disjoint 64-row tiles, reads precede writes)
    aggregate<<<gAgg, blk, 0, stream>>>(h1, csre, ptr, invd, agg);
    gemm_fused<<<gGemm, blk, 0, stream>>>(agg, h1, Wl1, Wr1, bl1, out, 1);
    // ---- layer 2: d_out -> d_out (no relu)
    aggregate<<<gAgg, blk, 0, stream>>>(out, csre, ptr, invd, agg);
    gemm_fused<<<gGemm, blk, 0, stream>>>(agg, out, Wl2, Wr2, bl2, out, 0);
}

// Round 6
// 1117.222 us; speedup vs baseline: 1.3369x; 1.3369x over previous
//
#include <hip/hip_runtime.h>
#include <hip/hip_bf16.h>

#define NN 100000
#define NE 1600000
#define DD 128

typedef __attribute__((ext_vector_type(8))) short bf16x8;
typedef __attribute__((ext_vector_type(4))) float f32x4;

// ---------------------------------------------------------------------------
// bf16 helpers (RNE, finite inputs)
__device__ __forceinline__ float bfu2f(unsigned short u) {
    unsigned v = ((unsigned)u) << 16;
    return __builtin_bit_cast(float, v);
}
__device__ __forceinline__ unsigned short f2bf(float f) {
    unsigned u = __builtin_bit_cast(unsigned, f);
    u += 0x7fffu + ((u >> 16) & 1u);
    return (unsigned short)(u >> 16);
}
__device__ __forceinline__ void split2(float v, unsigned short& hi, unsigned short& lo) {
    hi = f2bf(v);
    lo = f2bf(v - bfu2f(hi));
}
// packed-u32 (2 bf16) to floats: low ushort = even element, high = odd
__device__ __forceinline__ float lo_f(unsigned u) { return __builtin_bit_cast(float, u << 16); }
__device__ __forceinline__ float hi_f(unsigned u) { return __builtin_bit_cast(float, u & 0xffff0000u); }

// ---------------------------------------------------------------------------
// int64-vs-int32 edge_index detection (odd int32 words all zero <=> LE int64)
__global__ __launch_bounds__(256) void detect_kernel(const int* __restrict__ ei,
                                                     int* __restrict__ flag) {
    __shared__ int red[256];
    int t = threadIdx.x;
    int v = 0;
    for (int i = t; i < 4096; i += 256) v |= ei[2 * i + 1];
    red[t] = v;
    __syncthreads();
    for (int s = 128; s > 0; s >>= 1) {
        if (t < s) red[t] |= red[t + s];
        __syncthreads();
    }
    if (t == 0) flag[0] = (red[0] == 0) ? 1 : 0;
}

__device__ __forceinline__ int eidx(const int* __restrict__ ei, int idx, int is64) {
    return is64 ? ei[2 * idx] : ei[idx];
}

// ---------------------------------------------------------------------------
// CSR build: degree count -> exclusive scan -> cursor init -> fill
__global__ __launch_bounds__(256) void count_deg(const int* __restrict__ ei,
                                                 const int* __restrict__ flag,
                                                 int* __restrict__ deg) {
    int e = blockIdx.x * 256 + threadIdx.x;
    if (e < NE) {
        int is64 = flag[0];
        int dst = eidx(ei, NE + e, is64);
        atomicAdd(&deg[dst], 1);
    }
}

__global__ __launch_bounds__(1024) void scan_excl(const int* __restrict__ deg,
                                                  int* __restrict__ ptr) {
    __shared__ int wsum[16];
    __shared__ int carry_s;
    int t = threadIdx.x;
    int lane = t & 63, w = t >> 6;
    if (t == 0) carry_s = 0;
    __syncthreads();
    for (int base = 0; base < NN; base += 1024) {
        int i = base + t;
        int v = (i < NN) ? deg[i] : 0;
        int x = v;
        #pragma unroll
        for (int off = 1; off < 64; off <<= 1) {
            int y = __shfl_up(x, off, 64);
            if (lane >= off) x += y;
        }
        if (lane == 63) wsum[w] = x;
        __syncthreads();
        if (w == 0) {
            int s = (lane < 16) ? wsum[lane] : 0;
            #pragma unroll
            for (int off = 1; off < 16; off <<= 1) {
                int y = __shfl_up(s, off, 64);
                if (lane >= off) s += y;
            }
            if (lane < 16) wsum[lane] = s;
        }
        __syncthreads();
        int carry = carry_s;
        int woff = (w == 0) ? 0 : wsum[w - 1];
        if (i < NN) ptr[i] = carry + woff + (x - v);
        int chunk_total = wsum[15];
        __syncthreads();
        if (t == 0) carry_s = carry + chunk_total;
        __syncthreads();
    }
    if (threadIdx.x == 0) ptr[NN] = carry_s;
}

__global__ __launch_bounds__(256) void init_aux(const int* __restrict__ deg,
                                                const int* __restrict__ ptr,
                                                float* __restrict__ invd,
                                                int* __restrict__ cursor) {
    int i = blockIdx.x * 256 + threadIdx.x;
    if (i < NN) {
        int d = deg[i];
        invd[i] = 1.0f / (float)(d > 1 ? d : 1);
        cursor[i] = ptr[i];
    }
}

__global__ __launch_bounds__(256) void fill_csr(const int* __restrict__ ei,
                                                const int* __restrict__ flag,
                                                int* __restrict__ cursor,
                                                int* __restrict__ csre) {
    int e = blockIdx.x * 256 + threadIdx.x;
    if (e < NE) {
        int is64 = flag[0];
        int dst = eidx(ei, NE + e, is64);
        int src = eidx(ei, e, is64);
        int pos = atomicAdd(&cursor[dst], 1);
        csre[pos] = src;
    }
}

// ---------------------------------------------------------------------------
// x (fp32 [NN][128]) -> hi/lo bf16 packed-u32 [NN][64]
__global__ __launch_bounds__(256) void convert_x(const float* __restrict__ x,
                                                 unsigned* __restrict__ xh,
                                                 unsigned* __restrict__ xl) {
    int i = blockIdx.x * 256 + threadIdx.x;  // over NN*64 float2 pairs
    if (i >= NN * 64) return;
    float2 v = ((const float2*)x)[i];
    unsigned short h0, l0, h1, l1;
    split2(v.x, h0, l0);
    split2(v.y, h1, l1);
    xh[i] = (unsigned)h0 | ((unsigned)h1 << 16);
    xl[i] = (unsigned)l0 | ((unsigned)l1 << 16);
}

// W ([Wl;Wr] virtual [256][128]) -> transposed hi/lo bf16 Wt[n=128][k=256]
__global__ __launch_bounds__(256) void convert_w(const float* __restrict__ Wlm,
                                                 const float* __restrict__ Wrm,
                                                 unsigned short* __restrict__ Wth,
                                                 unsigned short* __restrict__ Wtl) {
    int i = blockIdx.x * 256 + threadIdx.x;  // 128*256
    if (i >= 128 * 256) return;
    int n = i >> 8, k = i & 255;
    float v = (k < 128) ? Wlm[k * 128 + n] : Wrm[(k - 128) * 128 + n];
    unsigned short h, l;
    split2(v, h, l);
    Wth[i] = h;
    Wtl[i] = l;
}

// ---------------------------------------------------------------------------
// Mean aggregation over hi/lo bf16 node features. One wave per node,
// u32 (2 bf16) per lane per array; fp32 accumulate; 4-way unrolled for MLP;
// writes agg as hi/lo bf16 pair. No atomics.
__global__ __launch_bounds__(256) void aggregate_bf(const unsigned* __restrict__ Hh,
                                                    const unsigned* __restrict__ Hl,
                                                    const int* __restrict__ csre,
                                                    const int* __restrict__ ptr,
                                                    const float* __restrict__ invd,
                                                    unsigned* __restrict__ Ah,
                                                    unsigned* __restrict__ Al) {
    int gw = blockIdx.x * 4 + (threadIdx.x >> 6);
    int lane = threadIdx.x & 63;
    if (gw >= NN) return;
    int beg = ptr[gw], end = ptr[gw + 1];
    float s00 = 0.f, s01 = 0.f, s10 = 0.f, s11 = 0.f;
    float s20 = 0.f, s21 = 0.f, s30 = 0.f, s31 = 0.f;
    int j = beg;
    for (; j + 4 <= end; j += 4) {
        int i0 = csre[j], i1 = csre[j + 1], i2 = csre[j + 2], i3 = csre[j + 3];
        unsigned h0 = Hh[(size_t)i0 * 64 + lane], g0 = Hl[(size_t)i0 * 64 + lane];
        unsigned h1 = Hh[(size_t)i1 * 64 + lane], g1 = Hl[(size_t)i1 * 64 + lane];
        unsigned h2 = Hh[(size_t)i2 * 64 + lane], g2 = Hl[(size_t)i2 * 64 + lane];
        unsigned h3 = Hh[(size_t)i3 * 64 + lane], g3 = Hl[(size_t)i3 * 64 + lane];
        s00 += lo_f(h0) + lo_f(g0); s01 += hi_f(h0) + hi_f(g0);
        s10 += lo_f(h1) + lo_f(g1); s11 += hi_f(h1) + hi_f(g1);
        s20 += lo_f(h2) + lo_f(g2); s21 += hi_f(h2) + hi_f(g2);
        s30 += lo_f(h3) + lo_f(g3); s31 += hi_f(h3) + hi_f(g3);
    }
    for (; j < end; ++j) {
        int i0 = csre[j];
        unsigned h0 = Hh[(size_t)i0 * 64 + lane], g0 = Hl[(size_t)i0 * 64 + lane];
        s00 += lo_f(h0) + lo_f(g0);
        s01 += hi_f(h0) + hi_f(g0);
    }
    float s = invd[gw];
    float v0 = ((s00 + s10) + (s20 + s30)) * s;
    float v1 = ((s01 + s11) + (s21 + s31)) * s;
    unsigned short h0_, l0_, h1_, l1_;
    split2(v0, h0_, l0_);
    split2(v1, h1_, l1_);
    Ah[(size_t)gw * 64 + lane] = (unsigned)h0_ | ((unsigned)h1_ << 16);
    Al[(size_t)gw * 64 + lane] = (unsigned)l0_ | ((unsigned)l1_ << 16);
}

// ---------------------------------------------------------------------------
// MFMA GEMM with split-bf16 (3-term): C[64 x 128] = [A0|A1] @ Wt^T + bias
// A0/A1: hi/lo bf16 [NN][128]; Wt: hi/lo bf16 [n=128][k=256].
// Block = 4 waves; wave w owns rows m0..m0+15 (16x16 tiles x 8 col-tiles).
// Fragment layouts (m89-verified): A lane l: A[l&15][(l>>4)*8+j];
// B from Wt symmetric; D lane l reg r: D[(l>>4)*4+r][l&15].
// mode 0: relu, write hi/lo bf16. mode 1: no relu, write fp32.
__global__ __launch_bounds__(256) void gemm_mfma(const unsigned short* __restrict__ A0h,
                                                 const unsigned short* __restrict__ A0l,
                                                 const unsigned short* __restrict__ A1h,
                                                 const unsigned short* __restrict__ A1l,
                                                 const unsigned short* __restrict__ Wh,
                                                 const unsigned short* __restrict__ Wl_,
                                                 const float* __restrict__ bias,
                                                 unsigned short* __restrict__ Oh,
                                                 unsigned short* __restrict__ Ol,
                                                 float* __restrict__ Of,
                                                 int mode) {
    int t = threadIdx.x;
    int w = t >> 6, l = t & 63;
    int lr = l & 15, lh = l >> 4;
    int m0 = blockIdx.x * 64 + w * 16;
    int ra = m0 + lr;
    if (ra >= NN) ra = NN - 1;
    const char* pa0h = (const char*)A0h + (size_t)ra * 256;
    const char* pa0l = (const char*)A0l + (size_t)ra * 256;
    const char* pa1h = (const char*)A1h + (size_t)ra * 256;
    const char* pa1l = (const char*)A1l + (size_t)ra * 256;
    bf16x8 ah[8], al[8];
    #pragma unroll
    for (int s = 0; s < 4; ++s) {
        int off = s * 64 + lh * 16;
        ah[s]     = *(const bf16x8*)(pa0h + off);
        al[s]     = *(const bf16x8*)(pa0l + off);
        ah[s + 4] = *(const bf16x8*)(pa1h + off);
        al[s + 4] = *(const bf16x8*)(pa1l + off);
    }
    #pragma unroll
    for (int ct = 0; ct < 8; ++ct) {
        int colr = ct * 16 + lr;
        const char* pbh = (const char*)Wh + (size_t)colr * 512;
        const char* pbl = (const char*)Wl_ + (size_t)colr * 512;
        f32x4 acc = {0.f, 0.f, 0.f, 0.f};
        #pragma unroll
        for (int s = 0; s < 8; ++s) {
            int off = s * 64 + lh * 16;
            bf16x8 bh = *(const bf16x8*)(pbh + off);
            bf16x8 bl = *(const bf16x8*)(pbl + off);
            acc = __builtin_amdgcn_mfma_f32_16x16x32_bf16(ah[s], bh, acc, 0, 0, 0);
            acc = __builtin_amdgcn_mfma_f32_16x16x32_bf16(ah[s], bl, acc, 0, 0, 0);
            acc = __builtin_amdgcn_mfma_f32_16x16x32_bf16(al[s], bh, acc, 0, 0, 0);
        }
        float bv = bias[colr];
        #pragma unroll
        for (int r = 0; r < 4; ++r) {
            int row = m0 + lh * 4 + r;
            if (row < NN) {
                float v = acc[r] + bv;
                if (mode == 0) {
                    v = fmaxf(v, 0.f);
                    unsigned short hh, ll;
                    split2(v, hh, ll);
                    Oh[(size_t)row * 128 + colr] = hh;
                    Ol[(size_t)row * 128 + colr] = ll;
                } else {
                    Of[(size_t)row * 128 + colr] = v;
                }
            }
        }
    }
}

// ---------------------------------------------------------------------------
extern "C" void kernel_launch(void* const* d_in, const int* in_sizes, int n_in,
                              void* d_out, int out_size, void* d_ws, size_t ws_size,
                              hipStream_t stream) {
    const float* x   = (const float*)d_in[0];
    const int*   ei  = (const int*)d_in[1];
    const float* Wl0 = (const float*)d_in[2];
    const float* bl0 = (const float*)d_in[3];
    const float* Wr0 = (const float*)d_in[4];
    const float* Wl1 = (const float*)d_in[5];
    const float* bl1 = (const float*)d_in[6];
    const float* Wr1 = (const float*)d_in[7];
    const float* Wl2 = (const float*)d_in[8];
    const float* bl2 = (const float*)d_in[9];
    const float* Wr2 = (const float*)d_in[10];
    float* out = (float*)d_out;

    char* p = (char*)d_ws;
    auto alloc = [&](size_t bytes) {
        char* q = p;
        p += (bytes + 255) & ~(size_t)255;
        return q;
    };
    int*   deg    = (int*)alloc((size_t)NN * 4);
    int*   ptr    = (int*)alloc((size_t)(NN + 1) * 4);
    int*   cursor = (int*)alloc((size_t)NN * 4);
    int*   csre   = (int*)alloc((size_t)NE * 4);
    float* invd   = (float*)alloc((size_t)NN * 4);
    int*   flag   = (int*)alloc(256);
    unsigned short* Wth0 = (unsigned short*)alloc(128 * 256 * 2);
    unsigned short* Wtl0 = (unsigned short*)alloc(128 * 256 * 2);
    unsigned short* Wth1 = (unsigned short*)alloc(128 * 256 * 2);
    unsigned short* Wtl1 = (unsigned short*)alloc(128 * 256 * 2);
    unsigned short* Wth2 = (unsigned short*)alloc(128 * 256 * 2);
    unsigned short* Wtl2 = (unsigned short*)alloc(128 * 256 * 2);
    unsigned* xh   = (unsigned*)alloc((size_t)NN * 64 * 4);  // also h2
    unsigned* xl   = (unsigned*)alloc((size_t)NN * 64 * 4);
    unsigned* aggh = (unsigned*)alloc((size_t)NN * 64 * 4);
    unsigned* aggl = (unsigned*)alloc((size_t)NN * 64 * 4);
    // h1 lives in d_out's bytes (dead before the final fp32 write)
    unsigned* h1h = (unsigned*)d_out;
    unsigned* h1l = h1h + (size_t)NN * 64;

    // ---- CSR build (structure shared by all 3 layers)
    hipMemsetAsync(deg, 0, (size_t)NN * 4, stream);
    detect_kernel<<<1, 256, 0, stream>>>(ei, flag);
    count_deg<<<(NE + 255) / 256, 256, 0, stream>>>(ei, flag, deg);
    scan_excl<<<1, 1024, 0, stream>>>(deg, ptr);
    init_aux<<<(NN + 255) / 256, 256, 0, stream>>>(deg, ptr, invd, cursor);
    fill_csr<<<(NE + 255) / 256, 256, 0, stream>>>(ei, flag, cursor, csre);

    // ---- operand conversion
    convert_x<<<(NN * 64 + 255) / 256, 256, 0, stream>>>(x, xh, xl);
    convert_w<<<128, 256, 0, stream>>>(Wl0, Wr0, Wth0, Wtl0);
    convert_w<<<128, 256, 0, stream>>>(Wl1, Wr1, Wth1, Wtl1);
    convert_w<<<128, 256, 0, stream>>>(Wl2, Wr2, Wth2, Wtl2);

    dim3 blk(256);
    dim3 gAgg(NN / 4);
    dim3 gGemm((NN + 63) / 64);

    // ---- layer 0: x -> h1 (relu), h1 stored in d_out bytes
    aggregate_bf<<<gAgg, blk, 0, stream>>>(xh, xl, csre, ptr, invd, aggh, aggl);
    gemm_mfma<<<gGemm, blk, 0, stream>>>((unsigned short*)aggh, (unsigned short*)aggl,
                                         (unsigned short*)xh, (unsigned short*)xl,
                                         Wth0, Wtl0, bl0,
                                         (unsigned short*)h1h, (unsigned short*)h1l,
                                         nullptr, 0);
    // ---- layer 1: h1 -> h2 (relu), h2 reuses x buffers
    aggregate_bf<<<gAgg, blk, 0, stream>>>(h1h, h1l, csre, ptr, invd, aggh, aggl);
    gemm_mfma<<<gGemm, blk, 0, stream>>>((unsigned short*)aggh, (unsigned short*)aggl,
                                         (unsigned short*)h1h, (unsigned short*)h1l,
                                         Wth1, Wtl1, bl1,
                                         (unsigned short*)xh, (unsigned short*)xl,
                                         nullptr, 0);
    // ---- layer 2: h2 -> out (fp32, no relu)
    aggregate_bf<<<gAgg, blk, 0, stream>>>(xh, xl, csre, ptr, invd, aggh, aggl);
    gemm_mfma<<<gGemm, blk, 0, stream>>>((unsigned short*)aggh, (unsigned short*)aggl,
                                         (unsigned short*)xh, (unsigned short*)xl,
                                         Wth2, Wtl2, bl2,
                                         nullptr, nullptr, out, 1);
}

// Round 8
// 1006.380 us; speedup vs baseline: 1.4842x; 1.1101x over previous
//
#include <hip/hip_runtime.h>
#include <hip/hip_bf16.h>

#define NN 100000
#define NE 1600000
#define DD 128

typedef __attribute__((ext_vector_type(8))) short bf16x8;
typedef __attribute__((ext_vector_type(4))) float f32x4;

// ---------------------------------------------------------------------------
// Feature-row layout: one node row = 128 u32 words (512 B):
//   words [0..63]  = hi-plane  (2 bf16 per word, features 2w, 2w+1)
//   words [64..127]= lo-plane  (same packing)
// ---------------------------------------------------------------------------

// bf16 helpers (RNE, finite inputs)
__device__ __forceinline__ float bfu2f(unsigned short u) {
    unsigned v = ((unsigned)u) << 16;
    return __builtin_bit_cast(float, v);
}
__device__ __forceinline__ unsigned short f2bf(float f) {
    unsigned u = __builtin_bit_cast(unsigned, f);
    u += 0x7fffu + ((u >> 16) & 1u);
    return (unsigned short)(u >> 16);
}
__device__ __forceinline__ void split2(float v, unsigned short& hi, unsigned short& lo) {
    hi = f2bf(v);
    lo = f2bf(v - bfu2f(hi));
}
__device__ __forceinline__ float lo_f(unsigned u) { return __builtin_bit_cast(float, u << 16); }
__device__ __forceinline__ float hi_f(unsigned u) { return __builtin_bit_cast(float, u & 0xffff0000u); }

// ---------------------------------------------------------------------------
// int64-vs-int32 edge_index detection (odd int32 words all zero <=> LE int64)
__global__ __launch_bounds__(256) void detect_kernel(const int* __restrict__ ei,
                                                     int* __restrict__ flag) {
    __shared__ int red[256];
    int t = threadIdx.x;
    int v = 0;
    for (int i = t; i < 4096; i += 256) v |= ei[2 * i + 1];
    red[t] = v;
    __syncthreads();
    for (int s = 128; s > 0; s >>= 1) {
        if (t < s) red[t] |= red[t + s];
        __syncthreads();
    }
    if (t == 0) flag[0] = (red[0] == 0) ? 1 : 0;
}

__device__ __forceinline__ int eidx(const int* __restrict__ ei, int idx, int is64) {
    return is64 ? ei[2 * idx] : ei[idx];
}

// ---------------------------------------------------------------------------
// CSR build: degree count -> 2-level scan -> finalize -> fill
__global__ __launch_bounds__(256) void count_deg(const int* __restrict__ ei,
                                                 const int* __restrict__ flag,
                                                 int* __restrict__ deg) {
    int e = blockIdx.x * 256 + threadIdx.x;
    if (e < NE) {
        int is64 = flag[0];
        int dst = eidx(ei, NE + e, is64);
        atomicAdd(&deg[dst], 1);
    }
}

// 98 blocks x 1024: per-block exclusive scan of deg into ptr, block totals to bsum
__global__ __launch_bounds__(1024) void scan_part(const int* __restrict__ deg,
                                                  int* __restrict__ ptr,
                                                  int* __restrict__ bsum) {
    __shared__ int ws[16];
    int t = threadIdx.x, lane = t & 63, w = t >> 6;
    int i = blockIdx.x * 1024 + t;
    int v = (i < NN) ? deg[i] : 0;
    int x = v;
    #pragma unroll
    for (int off = 1; off < 64; off <<= 1) {
        int y = __shfl_up(x, off, 64);
        if (lane >= off) x += y;
    }
    if (lane == 63) ws[w] = x;
    __syncthreads();
    if (w == 0) {
        int s = (lane < 16) ? ws[lane] : 0;
        #pragma unroll
        for (int off = 1; off < 16; off <<= 1) {
            int y = __shfl_up(s, off, 64);
            if (lane >= off) s += y;
        }
        if (lane < 16) ws[lane] = s;  // inclusive wave-sum scan
    }
    __syncthreads();
    int woff = (w == 0) ? 0 : ws[w - 1];
    if (i < NN) ptr[i] = woff + (x - v);
    if (t == 1023) bsum[blockIdx.x] = ws[15];
}

// 1 block x 128: exclusive scan of the 98 block sums in place
__global__ __launch_bounds__(128) void scan_top(int* __restrict__ bsum) {
    __shared__ int wt[2];
    int t = threadIdx.x, lane = t & 63, w = t >> 6;
    int v = (t < 98) ? bsum[t] : 0;
    int x = v;
    #pragma unroll
    for (int off = 1; off < 64; off <<= 1) {
        int y = __shfl_up(x, off, 64);
        if (lane >= off) x += y;
    }
    if (lane == 63) wt[w] = x;
    __syncthreads();
    int add = (w == 1) ? wt[0] : 0;
    if (t < 98) bsum[t] = add + (x - v);
}

// finalize: global ptr, cursor copy, invd; ptr[NN] = NE (every dst in range)
__global__ __launch_bounds__(256) void scan_final(const int* __restrict__ deg,
                                                  const int* __restrict__ bsum,
                                                  int* __restrict__ ptr,
                                                  float* __restrict__ invd,
                                                  int* __restrict__ cursor) {
    int i = blockIdx.x * 256 + threadIdx.x;
    if (i < NN) {
        int p = ptr[i] + bsum[i >> 10];
        ptr[i] = p;
        cursor[i] = p;
        int d = deg[i];
        invd[i] = 1.0f / (float)(d > 1 ? d : 1);
    }
    if (blockIdx.x == 0 && threadIdx.x == 0) ptr[NN] = NE;
}

__global__ __launch_bounds__(256) void fill_csr(const int* __restrict__ ei,
                                                const int* __restrict__ flag,
                                                int* __restrict__ cursor,
                                                int* __restrict__ csre) {
    int e = blockIdx.x * 256 + threadIdx.x;
    if (e < NE) {
        int is64 = flag[0];
        int dst = eidx(ei, NE + e, is64);
        int src = eidx(ei, e, is64);
        int pos = atomicAdd(&cursor[dst], 1);
        csre[pos] = src;
    }
}

// ---------------------------------------------------------------------------
// x (fp32 [NN][128]) -> interleaved hi|lo rows (u32 [NN][128])
__global__ __launch_bounds__(256) void convert_x(const float* __restrict__ x,
                                                 unsigned* __restrict__ H) {
    int i = blockIdx.x * 256 + threadIdx.x;  // over NN*64 float2 pairs
    if (i >= NN * 64) return;
    float2 v = ((const float2*)x)[i];
    unsigned short h0, l0, h1, l1;
    split2(v.x, h0, l0);
    split2(v.y, h1, l1);
    int n = i >> 6, w = i & 63;
    H[(size_t)n * 128 + w]      = (unsigned)h0 | ((unsigned)h1 << 16);
    H[(size_t)n * 128 + 64 + w] = (unsigned)l0 | ((unsigned)l1 << 16);
}

// W ([Wl;Wr] virtual [256][128]) -> transposed hi/lo bf16 Wt[n=128][k=256]
__global__ __launch_bounds__(256) void convert_w(const float* __restrict__ Wlm,
                                                 const float* __restrict__ Wrm,
                                                 unsigned short* __restrict__ Wth,
                                                 unsigned short* __restrict__ Wtl) {
    int i = blockIdx.x * 256 + threadIdx.x;  // 128*256
    if (i >= 128 * 256) return;
    int n = i >> 8, k = i & 255;
    float v = (k < 128) ? Wlm[k * 128 + n] : Wrm[(k - 128) * 128 + n];
    unsigned short h, l;
    split2(v, h, l);
    Wth[i] = h;
    Wtl[i] = l;
}

// ---------------------------------------------------------------------------
// Mean aggregation over interleaved rows. One wave per node; lane loads one
// uint2 (words 2l,2l+1) per edge: lanes<32 cover the hi-plane, lanes>=32 the
// lo-plane. fp32 accumulate, one shfl_xor(32) to merge planes, coalesced
// 512B wave store. 8-way unrolled. No atomics.
__global__ __launch_bounds__(256) void aggregate_bf(const unsigned* __restrict__ H,
                                                    const int* __restrict__ csre,
                                                    const int* __restrict__ ptr,
                                                    const float* __restrict__ invd,
                                                    unsigned* __restrict__ A) {
    int gw = blockIdx.x * 4 + (threadIdx.x >> 6);
    int lane = threadIdx.x & 63;
    if (gw >= NN) return;
    int beg = ptr[gw], end = ptr[gw + 1];
    float s0 = 0.f, s1 = 0.f, s2 = 0.f, s3 = 0.f;
    int j = beg;
    for (; j + 8 <= end; j += 8) {
        int idx[8];
        #pragma unroll
        for (int q = 0; q < 8; ++q) idx[q] = csre[j + q];
        uint2 r[8];
        #pragma unroll
        for (int q = 0; q < 8; ++q)
            r[q] = *(const uint2*)(H + (size_t)idx[q] * 128 + lane * 2);
        #pragma unroll
        for (int q = 0; q < 8; ++q) {
            s0 += lo_f(r[q].x);
            s1 += hi_f(r[q].x);
            s2 += lo_f(r[q].y);
            s3 += hi_f(r[q].y);
        }
    }
    for (; j < end; ++j) {
        uint2 r = *(const uint2*)(H + (size_t)csre[j] * 128 + lane * 2);
        s0 += lo_f(r.x);
        s1 += hi_f(r.x);
        s2 += lo_f(r.y);
        s3 += hi_f(r.y);
    }
    // merge hi-plane (lanes<32) with lo-plane (lanes>=32) sums: lane l and
    // l^32 hold the same 4 features' partial sums
    s0 += __shfl_xor(s0, 32, 64);
    s1 += __shfl_xor(s1, 32, 64);
    s2 += __shfl_xor(s2, 32, 64);
    s3 += __shfl_xor(s3, 32, 64);
    float sc = invd[gw];
    float t0 = s0 * sc, t1 = s1 * sc, t2 = s2 * sc, t3 = s3 * sc;
    unsigned short h0, l0, h1, l1, h2, l2, h3, l3;
    split2(t0, h0, l0);
    split2(t1, h1, l1);
    split2(t2, h2, l2);
    split2(t3, h3, l3);
    unsigned w0, w1;
    if (lane < 32) {  // write hi words 2l, 2l+1
        w0 = (unsigned)h0 | ((unsigned)h1 << 16);
        w1 = (unsigned)h2 | ((unsigned)h3 << 16);
    } else {          // write lo words 2l, 2l+1 (= lo-plane of features 4(l-32)..)
        w0 = (unsigned)l0 | ((unsigned)l1 << 16);
        w1 = (unsigned)l2 | ((unsigned)l3 << 16);
    }
    *(uint2*)(A + (size_t)gw * 128 + lane * 2) = make_uint2(w0, w1);
}

// ---------------------------------------------------------------------------
// MFMA GEMM with split-bf16 (3-term): C[64 x 128] = [A0|A1] @ Wt^T + bias
// A0/A1: interleaved hi|lo rows (512B). Wt: hi/lo bf16 [n=128][k=256].
// Fragment layouts (m89-verified): A lane l: A[l&15][(l>>4)*8+j];
// B from Wt symmetric; D lane l reg r: D[(l>>4)*4+r][l&15].
// mode 0: relu, write interleaved hi|lo rows. mode 1: no relu, write fp32.
__global__ __launch_bounds__(256) void gemm_mfma(const unsigned* __restrict__ A0,
                                                 const unsigned* __restrict__ A1,
                                                 const unsigned short* __restrict__ Wh,
                                                 const unsigned short* __restrict__ Wl_,
                                                 const float* __restrict__ bias,
                                                 unsigned* __restrict__ O,
                                                 float* __restrict__ Of,
                                                 int mode) {
    int t = threadIdx.x;
    int w = t >> 6, l = t & 63;
    int lr = l & 15, lh = l >> 4;
    int m0 = blockIdx.x * 64 + w * 16;
    int ra = m0 + lr;
    if (ra >= NN) ra = NN - 1;
    const char* pa0 = (const char*)(A0 + (size_t)ra * 128);
    const char* pa1 = (const char*)(A1 + (size_t)ra * 128);
    bf16x8 ah[8], al[8];
    #pragma unroll
    for (int s = 0; s < 4; ++s) {
        int off = s * 64 + lh * 16;
        ah[s]     = *(const bf16x8*)(pa0 + off);
        al[s]     = *(const bf16x8*)(pa0 + 256 + off);
        ah[s + 4] = *(const bf16x8*)(pa1 + off);
        al[s + 4] = *(const bf16x8*)(pa1 + 256 + off);
    }
    float bv[8];
    #pragma unroll
    for (int ct = 0; ct < 8; ++ct) bv[ct] = bias[ct * 16 + lr];
    #pragma unroll
    for (int ct = 0; ct < 8; ++ct) {
        int colr = ct * 16 + lr;
        const char* pbh = (const char*)Wh + (size_t)colr * 512;
        const char* pbl = (const char*)Wl_ + (size_t)colr * 512;
        f32x4 acc = {0.f, 0.f, 0.f, 0.f};
        #pragma unroll
        for (int s = 0; s < 8; ++s) {
            int off = s * 64 + lh * 16;
            bf16x8 bh = *(const bf16x8*)(pbh + off);
            bf16x8 bl = *(const bf16x8*)(pbl + off);
            acc = __builtin_amdgcn_mfma_f32_16x16x32_bf16(ah[s], bh, acc, 0, 0, 0);
            acc = __builtin_amdgcn_mfma_f32_16x16x32_bf16(ah[s], bl, acc, 0, 0, 0);
            acc = __builtin_amdgcn_mfma_f32_16x16x32_bf16(al[s], bh, acc, 0, 0, 0);
        }
        #pragma unroll
        for (int r = 0; r < 4; ++r) {
            int row = m0 + lh * 4 + r;
            if (row < NN) {
                float v = acc[r] + bv[ct];
                if (mode == 0) {
                    v = fmaxf(v, 0.f);
                    unsigned short hh, ll;
                    split2(v, hh, ll);
                    char* po = (char*)(O + (size_t)row * 128);
                    *(unsigned short*)(po + colr * 2) = hh;
                    *(unsigned short*)(po + 256 + colr * 2) = ll;
                } else {
                    Of[(size_t)row * 128 + colr] = v;
                }
            }
        }
    }
}

// ---------------------------------------------------------------------------
extern "C" void kernel_launch(void* const* d_in, const int* in_sizes, int n_in,
                              void* d_out, int out_size, void* d_ws, size_t ws_size,
                              hipStream_t stream) {
    const float* x   = (const float*)d_in[0];
    const int*   ei  = (const int*)d_in[1];
    const float* Wl0 = (const float*)d_in[2];
    const float* bl0 = (const float*)d_in[3];
    const float* Wr0 = (const float*)d_in[4];
    const float* Wl1 = (const float*)d_in[5];
    const float* bl1 = (const float*)d_in[6];
    const float* Wr1 = (const float*)d_in[7];
    const float* Wl2 = (const float*)d_in[8];
    const float* bl2 = (const float*)d_in[9];
    const float* Wr2 = (const float*)d_in[10];
    float* out = (float*)d_out;

    char* p = (char*)d_ws;
    auto alloc = [&](size_t bytes) {
        char* q = p;
        p += (bytes + 255) & ~(size_t)255;
        return q;
    };
    int*   deg    = (int*)alloc((size_t)NN * 4);
    int*   ptr    = (int*)alloc((size_t)(NN + 1) * 4);
    int*   cursor = (int*)alloc((size_t)NN * 4);
    int*   csre   = (int*)alloc((size_t)NE * 4);
    float* invd   = (float*)alloc((size_t)NN * 4);
    int*   flag   = (int*)alloc(256);
    int*   bsum   = (int*)alloc(128 * 4);
    unsigned short* Wth0 = (unsigned short*)alloc(128 * 256 * 2);
    unsigned short* Wtl0 = (unsigned short*)alloc(128 * 256 * 2);
    unsigned short* Wth1 = (unsigned short*)alloc(128 * 256 * 2);
    unsigned short* Wtl1 = (unsigned short*)alloc(128 * 256 * 2);
    unsigned short* Wth2 = (unsigned short*)alloc(128 * 256 * 2);
    unsigned short* Wtl2 = (unsigned short*)alloc(128 * 256 * 2);
    unsigned* xH   = (unsigned*)alloc((size_t)NN * 128 * 4);  // also h2
    unsigned* aggH = (unsigned*)alloc((size_t)NN * 128 * 4);
    // h1 lives in d_out's bytes (51.2 MB = NN*512B exactly; dead before the
    // final fp32 write)
    unsigned* h1H = (unsigned*)d_out;

    // ---- CSR build (structure shared by all 3 layers)
    hipMemsetAsync(deg, 0, (size_t)NN * 4, stream);
    detect_kernel<<<1, 256, 0, stream>>>(ei, flag);
    count_deg<<<(NE + 255) / 256, 256, 0, stream>>>(ei, flag, deg);
    scan_part<<<(NN + 1023) / 1024, 1024, 0, stream>>>(deg, ptr, bsum);
    scan_top<<<1, 128, 0, stream>>>(bsum);
    scan_final<<<(NN + 255) / 256, 256, 0, stream>>>(deg, bsum, ptr, invd, cursor);
    fill_csr<<<(NE + 255) / 256, 256, 0, stream>>>(ei, flag, cursor, csre);

    // ---- operand conversion
    convert_x<<<(NN * 64 + 255) / 256, 256, 0, stream>>>(x, xH);
    convert_w<<<128, 256, 0, stream>>>(Wl0, Wr0, Wth0, Wtl0);
    convert_w<<<128, 256, 0, stream>>>(Wl1, Wr1, Wth1, Wtl1);
    convert_w<<<128, 256, 0, stream>>>(Wl2, Wr2, Wth2, Wtl2);

    dim3 blk(256);
    dim3 gAgg(NN / 4);
    dim3 gGemm((NN + 63) / 64);

    // ---- layer 0: x -> h1 (relu), h1 stored in d_out bytes
    aggregate_bf<<<gAgg, blk, 0, stream>>>(xH, csre, ptr, invd, aggH);
    gemm_mfma<<<gGemm, blk, 0, stream>>>(aggH, xH, Wth0, Wtl0, bl0, h1H, nullptr, 0);
    // ---- layer 1: h1 -> h2 (relu), h2 reuses xH (dead after layer-0 gemm)
    aggregate_bf<<<gAgg, blk, 0, stream>>>(h1H, csre, ptr, invd, aggH);
    gemm_mfma<<<gGemm, blk, 0, stream>>>(aggH, h1H, Wth1, Wtl1, bl1, xH, nullptr, 0);
    // ---- layer 2: h2 -> out (fp32, no relu); h1H (d_out bytes) dead by now
    aggregate_bf<<<gAgg, blk, 0, stream>>>(xH, csre, ptr, invd, aggH);
    gemm_mfma<<<gGemm, blk, 0, stream>>>(aggH, xH, Wth2, Wtl2, bl2, nullptr, out, 1);
}

// Round 10
// 975.746 us; speedup vs baseline: 1.5308x; 1.0314x over previous
//
#include <hip/hip_runtime.h>
#include <hip/hip_bf16.h>

#define NN 100000
#define NE 1600000
#define DD 128
#define NSLICE 1000
#define SLICE_E 1600   // NSLICE * SLICE_E == NE
#define RNG (NN / 8)   // 12500 dst-nodes per XCD range

typedef __attribute__((ext_vector_type(8))) short bf16x8;
typedef __attribute__((ext_vector_type(4))) float f32x4;

// ---------------------------------------------------------------------------
// Feature-row layout: one node row = 128 u32 words (512 B):
//   words [0..63]  = hi-plane  (2 bf16 per word, features 2w, 2w+1)
//   words [64..127]= lo-plane  (same packing)
// ---------------------------------------------------------------------------

// bf16 helpers (RNE, finite inputs)
__device__ __forceinline__ float bfu2f(unsigned short u) {
    unsigned v = ((unsigned)u) << 16;
    return __builtin_bit_cast(float, v);
}
__device__ __forceinline__ unsigned short f2bf(float f) {
    unsigned u = __builtin_bit_cast(unsigned, f);
    u += 0x7fffu + ((u >> 16) & 1u);
    return (unsigned short)(u >> 16);
}
__device__ __forceinline__ void split2(float v, unsigned short& hi, unsigned short& lo) {
    hi = f2bf(v);
    lo = f2bf(v - bfu2f(hi));
}
__device__ __forceinline__ float lo_f(unsigned u) { return __builtin_bit_cast(float, u << 16); }
__device__ __forceinline__ float hi_f(unsigned u) { return __builtin_bit_cast(float, u & 0xffff0000u); }

// ---------------------------------------------------------------------------
// int64-vs-int32 edge_index detection (odd int32 words all zero <=> LE int64)
__global__ __launch_bounds__(256) void detect_kernel(const int* __restrict__ ei,
                                                     int* __restrict__ flag) {
    __shared__ int red[256];
    int t = threadIdx.x;
    int v = 0;
    for (int i = t; i < 4096; i += 256) v |= ei[2 * i + 1];
    red[t] = v;
    __syncthreads();
    for (int s = 128; s > 0; s >>= 1) {
        if (t < s) red[t] |= red[t + s];
        __syncthreads();
    }
    if (t == 0) flag[0] = (red[0] == 0) ? 1 : 0;
}

__device__ __forceinline__ int eidx(const int* __restrict__ ei, int idx, int is64) {
    return is64 ? ei[2 * idx] : ei[idx];
}

// ---------------------------------------------------------------------------
// XCD-partitioned CSR build. Grid = 8 ranges x NSLICE slices; block b scans
// edge slice (b>>3) and commits only dst in range (b&7). With round-robin
// blockIdx%8 -> XCD dispatch, each range's cursor atomics + csre writes stay
// in ONE XCD's L2 (800KB region), so 4B scatters merge into lines instead of
// draining one 64B line per edge to HBM (which was 105MB WRITE, 133us).
// Partition is exact regardless of XCD mapping; only locality depends on it.
__global__ __launch_bounds__(256) void count_deg_x(const int* __restrict__ ei,
                                                   const int* __restrict__ flag,
                                                   int* __restrict__ deg) {
    int b = blockIdx.x;
    int lo = (b & 7) * RNG, hi = lo + RNG;
    int e0 = (b >> 3) * SLICE_E;
    int is64 = flag[0];
    for (int e = e0 + threadIdx.x; e < e0 + SLICE_E; e += 256) {
        int dst = eidx(ei, NE + e, is64);
        if (dst >= lo && dst < hi) atomicAdd(&deg[dst], 1);
    }
}

__global__ __launch_bounds__(256) void fill_csr_x(const int* __restrict__ ei,
                                                  const int* __restrict__ flag,
                                                  int* __restrict__ cursor,
                                                  int* __restrict__ csre) {
    int b = blockIdx.x;
    int lo = (b & 7) * RNG, hi = lo + RNG;
    int e0 = (b >> 3) * SLICE_E;
    int is64 = flag[0];
    for (int e = e0 + threadIdx.x; e < e0 + SLICE_E; e += 256) {
        int dst = eidx(ei, NE + e, is64);
        if (dst >= lo && dst < hi) {
            int src = eidx(ei, e, is64);
            int pos = atomicAdd(&cursor[dst], 1);
            csre[pos] = src;
        }
    }
}

// 98 blocks x 1024: per-block exclusive scan of deg into ptr, block totals to bsum
__global__ __launch_bounds__(1024) void scan_part(const int* __restrict__ deg,
                                                  int* __restrict__ ptr,
                                                  int* __restrict__ bsum) {
    __shared__ int ws[16];
    int t = threadIdx.x, lane = t & 63, w = t >> 6;
    int i = blockIdx.x * 1024 + t;
    int v = (i < NN) ? deg[i] : 0;
    int x = v;
    #pragma unroll
    for (int off = 1; off < 64; off <<= 1) {
        int y = __shfl_up(x, off, 64);
        if (lane >= off) x += y;
    }
    if (lane == 63) ws[w] = x;
    __syncthreads();
    if (w == 0) {
        int s = (lane < 16) ? ws[lane] : 0;
        #pragma unroll
        for (int off = 1; off < 16; off <<= 1) {
            int y = __shfl_up(s, off, 64);
            if (lane >= off) s += y;
        }
        if (lane < 16) ws[lane] = s;  // inclusive wave-sum scan
    }
    __syncthreads();
    int woff = (w == 0) ? 0 : ws[w - 1];
    if (i < NN) ptr[i] = woff + (x - v);
    if (t == 1023) bsum[blockIdx.x] = ws[15];
}

// 1 block x 128: exclusive scan of the 98 block sums in place
__global__ __launch_bounds__(128) void scan_top(int* __restrict__ bsum) {
    __shared__ int wt[2];
    int t = threadIdx.x, lane = t & 63, w = t >> 6;
    int v = (t < 98) ? bsum[t] : 0;
    int x = v;
    #pragma unroll
    for (int off = 1; off < 64; off <<= 1) {
        int y = __shfl_up(x, off, 64);
        if (lane >= off) x += y;
    }
    if (lane == 63) wt[w] = x;
    __syncthreads();
    int add = (w == 1) ? wt[0] : 0;
    if (t < 98) bsum[t] = add + (x - v);
}

// finalize: global ptr, cursor copy, invd; ptr[NN] = NE (every dst in range)
__global__ __launch_bounds__(256) void scan_final(const int* __restrict__ deg,
                                                  const int* __restrict__ bsum,
                                                  int* __restrict__ ptr,
                                                  float* __restrict__ invd,
                                                  int* __restrict__ cursor) {
    int i = blockIdx.x * 256 + threadIdx.x;
    if (i < NN) {
        int p = ptr[i] + bsum[i >> 10];
        ptr[i] = p;
        cursor[i] = p;
        int d = deg[i];
        invd[i] = 1.0f / (float)(d > 1 ? d : 1);
    }
    if (blockIdx.x == 0 && threadIdx.x == 0) ptr[NN] = NE;
}

// ---------------------------------------------------------------------------
// x (fp32 [NN][128]) -> interleaved hi|lo rows (u32 [NN][128])
__global__ __launch_bounds__(256) void convert_x(const float* __restrict__ x,
                                                 unsigned* __restrict__ H) {
    int i = blockIdx.x * 256 + threadIdx.x;  // over NN*64 float2 pairs
    if (i >= NN * 64) return;
    float2 v = ((const float2*)x)[i];
    unsigned short h0, l0, h1, l1;
    split2(v.x, h0, l0);
    split2(v.y, h1, l1);
    int n = i >> 6, w = i & 63;
    H[(size_t)n * 128 + w]      = (unsigned)h0 | ((unsigned)h1 << 16);
    H[(size_t)n * 128 + 64 + w] = (unsigned)l0 | ((unsigned)l1 << 16);
}

// W ([Wl;Wr] virtual [256][128]) -> transposed hi/lo bf16 Wt[n=128][k=256]
__global__ __launch_bounds__(256) void convert_w(const float* __restrict__ Wlm,
                                                 const float* __restrict__ Wrm,
                                                 unsigned short* __restrict__ Wth,
                                                 unsigned short* __restrict__ Wtl) {
    int i = blockIdx.x * 256 + threadIdx.x;  // 128*256
    if (i >= 128 * 256) return;
    int n = i >> 8, k = i & 255;
    float v = (k < 128) ? Wlm[k * 128 + n] : Wrm[(k - 128) * 128 + n];
    unsigned short h, l;
    split2(v, h, l);
    Wth[i] = h;
    Wtl[i] = l;
}

// ---------------------------------------------------------------------------
// Mean aggregation over interleaved rows. One wave per node; lane loads one
// uint2 (words 2l,2l+1) per edge: lanes<32 cover the hi-plane, lanes>=32 the
// lo-plane. fp32 accumulate, one shfl_xor(32) to merge planes, coalesced
// 512B wave store. 8-way unrolled. No atomics.
__global__ __launch_bounds__(256) void aggregate_bf(const unsigned* __restrict__ H,
                                                    const int* __restrict__ csre,
                                                    const int* __restrict__ ptr,
                                                    const float* __restrict__ invd,
                                                    unsigned* __restrict__ A) {
    int gw = blockIdx.x * 4 + (threadIdx.x >> 6);
    int lane = threadIdx.x & 63;
    if (gw >= NN) return;
    int beg = ptr[gw], end = ptr[gw + 1];
    float s0 = 0.f, s1 = 0.f, s2 = 0.f, s3 = 0.f;
    int j = beg;
    for (; j + 8 <= end; j += 8) {
        int idx[8];
        #pragma unroll
        for (int q = 0; q < 8; ++q) idx[q] = csre[j + q];
        uint2 r[8];
        #pragma unroll
        for (int q = 0; q < 8; ++q)
            r[q] = *(const uint2*)(H + (size_t)idx[q] * 128 + lane * 2);
        #pragma unroll
        for (int q = 0; q < 8; ++q) {
            s0 += lo_f(r[q].x);
            s1 += hi_f(r[q].x);
            s2 += lo_f(r[q].y);
            s3 += hi_f(r[q].y);
        }
    }
    for (; j < end; ++j) {
        uint2 r = *(const uint2*)(H + (size_t)csre[j] * 128 + lane * 2);
        s0 += lo_f(r.x);
        s1 += hi_f(r.x);
        s2 += lo_f(r.y);
        s3 += hi_f(r.y);
    }
    // merge hi-plane (lanes<32) with lo-plane (lanes>=32) sums: lane l and
    // l^32 hold the same 4 features' partial sums
    s0 += __shfl_xor(s0, 32, 64);
    s1 += __shfl_xor(s1, 32, 64);
    s2 += __shfl_xor(s2, 32, 64);
    s3 += __shfl_xor(s3, 32, 64);
    float sc = invd[gw];
    float t0 = s0 * sc, t1 = s1 * sc, t2 = s2 * sc, t3 = s3 * sc;
    unsigned short h0, l0, h1, l1, h2, l2, h3, l3;
    split2(t0, h0, l0);
    split2(t1, h1, l1);
    split2(t2, h2, l2);
    split2(t3, h3, l3);
    unsigned w0, w1;
    if (lane < 32) {  // write hi words 2l, 2l+1
        w0 = (unsigned)h0 | ((unsigned)h1 << 16);
        w1 = (unsigned)h2 | ((unsigned)h3 << 16);
    } else {          // write lo words 2l, 2l+1 (= lo-plane of features 4(l-32)..)
        w0 = (unsigned)l0 | ((unsigned)l1 << 16);
        w1 = (unsigned)l2 | ((unsigned)l3 << 16);
    }
    *(uint2*)(A + (size_t)gw * 128 + lane * 2) = make_uint2(w0, w1);
}

// ---------------------------------------------------------------------------
// MFMA GEMM with split-bf16 (3-term): C[64 x 128] = [A0|A1] @ Wt^T + bias
// A0/A1: interleaved hi|lo rows (512B). Wt: hi/lo bf16 [n=128][k=256].
// Fragment layouts (m89-verified): A lane l: A[l&15][(l>>4)*8+j];
// B from Wt symmetric; D lane l reg r: D[(l>>4)*4+r][l&15].
// mode 0: relu, write interleaved hi|lo rows. mode 1: no relu, write fp32.
__global__ __launch_bounds__(256) void gemm_mfma(const unsigned* __restrict__ A0,
                                                 const unsigned* __restrict__ A1,
                                                 const unsigned short* __restrict__ Wh,
                                                 const unsigned short* __restrict__ Wl_,
                                                 const float* __restrict__ bias,
                                                 unsigned* __restrict__ O,
                                                 float* __restrict__ Of,
                                                 int mode) {
    int t = threadIdx.x;
    int w = t >> 6, l = t & 63;
    int lr = l & 15, lh = l >> 4;
    int m0 = blockIdx.x * 64 + w * 16;
    int ra = m0 + lr;
    if (ra >= NN) ra = NN - 1;
    const char* pa0 = (const char*)(A0 + (size_t)ra * 128);
    const char* pa1 = (const char*)(A1 + (size_t)ra * 128);
    bf16x8 ah[8], al[8];
    #pragma unroll
    for (int s = 0; s < 4; ++s) {
        int off = s * 64 + lh * 16;
        ah[s]     = *(const bf16x8*)(pa0 + off);
        al[s]     = *(const bf16x8*)(pa0 + 256 + off);
        ah[s + 4] = *(const bf16x8*)(pa1 + off);
        al[s + 4] = *(const bf16x8*)(pa1 + 256 + off);
    }
    float bv[8];
    #pragma unroll
    for (int ct = 0; ct < 8; ++ct) bv[ct] = bias[ct * 16 + lr];
    #pragma unroll
    for (int ct = 0; ct < 8; ++ct) {
        int colr = ct * 16 + lr;
        const char* pbh = (const char*)Wh + (size_t)colr * 512;
        const char* pbl = (const char*)Wl_ + (size_t)colr * 512;
        f32x4 acc = {0.f, 0.f, 0.f, 0.f};
        #pragma unroll
        for (int s = 0; s < 8; ++s) {
            int off = s * 64 + lh * 16;
            bf16x8 bh = *(const bf16x8*)(pbh + off);
            bf16x8 bl = *(const bf16x8*)(pbl + off);
            acc = __builtin_amdgcn_mfma_f32_16x16x32_bf16(ah[s], bh, acc, 0, 0, 0);
            acc = __builtin_amdgcn_mfma_f32_16x16x32_bf16(ah[s], bl, acc, 0, 0, 0);
            acc = __builtin_amdgcn_mfma_f32_16x16x32_bf16(al[s], bh, acc, 0, 0, 0);
        }
        #pragma unroll
        for (int r = 0; r < 4; ++r) {
            int row = m0 + lh * 4 + r;
            if (row < NN) {
                float v = acc[r] + bv[ct];
                if (mode == 0) {
                    v = fmaxf(v, 0.f);
                    unsigned short hh, ll;
                    split2(v, hh, ll);
                    char* po = (char*)(O + (size_t)row * 128);
                    *(unsigned short*)(po + colr * 2) = hh;
                    *(unsigned short*)(po + 256 + colr * 2) = ll;
                } else {
                    Of[(size_t)row * 128 + colr] = v;
                }
            }
        }
    }
}

// ---------------------------------------------------------------------------
extern "C" void kernel_launch(void* const* d_in, const int* in_sizes, int n_in,
                              void* d_out, int out_size, void* d_ws, size_t ws_size,
                              hipStream_t stream) {
    const float* x   = (const float*)d_in[0];
    const int*   ei  = (const int*)d_in[1];
    const float* Wl0 = (const float*)d_in[2];
    const float* bl0 = (const float*)d_in[3];
    const float* Wr0 = (const float*)d_in[4];
    const float* Wl1 = (const float*)d_in[5];
    const float* bl1 = (const float*)d_in[6];
    const float* Wr1 = (const float*)d_in[7];
    const float* Wl2 = (const float*)d_in[8];
    const float* bl2 = (const float*)d_in[9];
    const float* Wr2 = (const float*)d_in[10];
    float* out = (float*)d_out;

    char* p = (char*)d_ws;
    auto alloc = [&](size_t bytes) {
        char* q = p;
        p += (bytes + 255) & ~(size_t)255;
        return q;
    };
    int*   deg    = (int*)alloc((size_t)NN * 4);
    int*   ptr    = (int*)alloc((size_t)(NN + 1) * 4);
    int*   cursor = (int*)alloc((size_t)NN * 4);
    int*   csre   = (int*)alloc((size_t)NE * 4);
    float* invd   = (float*)alloc((size_t)NN * 4);
    int*   flag   = (int*)alloc(256);
    int*   bsum   = (int*)alloc(128 * 4);
    unsigned short* Wth0 = (unsigned short*)alloc(128 * 256 * 2);
    unsigned short* Wtl0 = (unsigned short*)alloc(128 * 256 * 2);
    unsigned short* Wth1 = (unsigned short*)alloc(128 * 256 * 2);
    unsigned short* Wtl1 = (unsigned short*)alloc(128 * 256 * 2);
    unsigned short* Wth2 = (unsigned short*)alloc(128 * 256 * 2);
    unsigned short* Wtl2 = (unsigned short*)alloc(128 * 256 * 2);
    unsigned* xH   = (unsigned*)alloc((size_t)NN * 128 * 4);  // also h2
    unsigned* aggH = (unsigned*)alloc((size_t)NN * 128 * 4);
    // h1 lives in d_out's bytes (51.2 MB = NN*512B exactly; dead before the
    // final fp32 write)
    unsigned* h1H = (unsigned*)d_out;

    // ---- CSR build (structure shared by all 3 layers)
    hipMemsetAsync(deg, 0, (size_t)NN * 4, stream);
    detect_kernel<<<1, 256, 0, stream>>>(ei, flag);
    count_deg_x<<<8 * NSLICE, 256, 0, stream>>>(ei, flag, deg);
    scan_part<<<(NN + 1023) / 1024, 1024, 0, stream>>>(deg, ptr, bsum);
    scan_top<<<1, 128, 0, stream>>>(bsum);
    scan_final<<<(NN + 255) / 256, 256, 0, stream>>>(deg, bsum, ptr, invd, cursor);
    fill_csr_x<<<8 * NSLICE, 256, 0, stream>>>(ei, flag, cursor, csre);

    // ---- operand conversion
    convert_x<<<(NN * 64 + 255) / 256, 256, 0, stream>>>(x, xH);
    convert_w<<<128, 256, 0, stream>>>(Wl0, Wr0, Wth0, Wtl0);
    convert_w<<<128, 256, 0, stream>>>(Wl1, Wr1, Wth1, Wtl1);
    convert_w<<<128, 256, 0, stream>>>(Wl2, Wr2, Wth2, Wtl2);

    dim3 blk(256);
    dim3 gAgg(NN / 4);
    dim3 gGemm((NN + 63) / 64);

    // ---- layer 0: x -> h1 (relu), h1 stored in d_out bytes
    aggregate_bf<<<gAgg, blk, 0, stream>>>(xH, csre, ptr, invd, aggH);
    gemm_mfma<<<gGemm, blk, 0, stream>>>(aggH, xH, Wth0, Wtl0, bl0, h1H, nullptr, 0);
    // ---- layer 1: h1 -> h2 (relu), h2 reuses xH (dead after layer-0 gemm)
    aggregate_bf<<<gAgg, blk, 0, stream>>>(h1H, csre, ptr, invd, aggH);
    gemm_mfma<<<gGemm, blk, 0, stream>>>(aggH, h1H, Wth1, Wtl1, bl1, xH, nullptr, 0);
    // ---- layer 2: h2 -> out (fp32, no relu); h1H (d_out bytes) dead by now
    aggregate_bf<<<gAgg, blk, 0, stream>>>(xH, csre, ptr, invd, aggH);
    gemm_mfma<<<gGemm, blk, 0, stream>>>(aggH, xH, Wth2, Wtl2, bl2, nullptr, out, 1);
}

// Round 15
// 969.870 us; speedup vs baseline: 1.5400x; 1.0061x over previous
//
#include <hip/hip_runtime.h>
#include <hip/hip_bf16.h>

#define NN 100000
#define NE 1600000
#define DD 128
#define NSLICE 1000
#define SLICE_E 1600   // NSLICE * SLICE_E == NE
#define RNG (NN / 8)   // 12500 dst-nodes per XCD range

typedef __attribute__((ext_vector_type(8))) short bf16x8;
typedef __attribute__((ext_vector_type(4))) float f32x4;

// ---------------------------------------------------------------------------
// Feature-row layout: one node row = 128 u32 words (512 B):
//   words [0..63]  = hi-plane  (2 bf16 per word, features 2w, 2w+1)
//   words [64..127]= lo-plane  (same packing)
// ---------------------------------------------------------------------------

// bf16 helpers (RNE, finite inputs)
__device__ __forceinline__ float bfu2f(unsigned short u) {
    unsigned v = ((unsigned)u) << 16;
    return __builtin_bit_cast(float, v);
}
__device__ __forceinline__ unsigned short f2bf(float f) {
    unsigned u = __builtin_bit_cast(unsigned, f);
    u += 0x7fffu + ((u >> 16) & 1u);
    return (unsigned short)(u >> 16);
}
__device__ __forceinline__ void split2(float v, unsigned short& hi, unsigned short& lo) {
    hi = f2bf(v);
    lo = f2bf(v - bfu2f(hi));
}
__device__ __forceinline__ float lo_f(unsigned u) { return __builtin_bit_cast(float, u << 16); }
__device__ __forceinline__ float hi_f(unsigned u) { return __builtin_bit_cast(float, u & 0xffff0000u); }

// ---------------------------------------------------------------------------
// int64-vs-int32 edge_index detection (odd int32 words all zero <=> LE int64)
__global__ __launch_bounds__(256) void detect_kernel(const int* __restrict__ ei,
                                                     int* __restrict__ flag) {
    __shared__ int red[256];
    int t = threadIdx.x;
    int v = 0;
    for (int i = t; i < 4096; i += 256) v |= ei[2 * i + 1];
    red[t] = v;
    __syncthreads();
    for (int s = 128; s > 0; s >>= 1) {
        if (t < s) red[t] |= red[t + s];
        __syncthreads();
    }
    if (t == 0) flag[0] = (red[0] == 0) ? 1 : 0;
}

__device__ __forceinline__ int eidx(const int* __restrict__ ei, int idx, int is64) {
    return is64 ? ei[2 * idx] : ei[idx];
}

// ---------------------------------------------------------------------------
// XCD-partitioned CSR build (see Round-9 notes: keeps each range's cursor
// atomics + csre writes in one XCD's L2 so 4B scatters merge before HBM).
__global__ __launch_bounds__(256) void count_deg_x(const int* __restrict__ ei,
                                                   const int* __restrict__ flag,
                                                   int* __restrict__ deg) {
    int b = blockIdx.x;
    int lo = (b & 7) * RNG, hi = lo + RNG;
    int e0 = (b >> 3) * SLICE_E;
    int is64 = flag[0];
    for (int e = e0 + threadIdx.x; e < e0 + SLICE_E; e += 256) {
        int dst = eidx(ei, NE + e, is64);
        if (dst >= lo && dst < hi) atomicAdd(&deg[dst], 1);
    }
}

__global__ __launch_bounds__(256) void fill_csr_x(const int* __restrict__ ei,
                                                  const int* __restrict__ flag,
                                                  int* __restrict__ cursor,
                                                  int* __restrict__ csre) {
    int b = blockIdx.x;
    int lo = (b & 7) * RNG, hi = lo + RNG;
    int e0 = (b >> 3) * SLICE_E;
    int is64 = flag[0];
    for (int e = e0 + threadIdx.x; e < e0 + SLICE_E; e += 256) {
        int dst = eidx(ei, NE + e, is64);
        if (dst >= lo && dst < hi) {
            int src = eidx(ei, e, is64);
            int pos = atomicAdd(&cursor[dst], 1);
            csre[pos] = src;
        }
    }
}

// 98 blocks x 1024: per-block exclusive scan of deg into ptr, block totals to bsum
__global__ __launch_bounds__(1024) void scan_part(const int* __restrict__ deg,
                                                  int* __restrict__ ptr,
                                                  int* __restrict__ bsum) {
    __shared__ int ws[16];
    int t = threadIdx.x, lane = t & 63, w = t >> 6;
    int i = blockIdx.x * 1024 + t;
    int v = (i < NN) ? deg[i] : 0;
    int x = v;
    #pragma unroll
    for (int off = 1; off < 64; off <<= 1) {
        int y = __shfl_up(x, off, 64);
        if (lane >= off) x += y;
    }
    if (lane == 63) ws[w] = x;
    __syncthreads();
    if (w == 0) {
        int s = (lane < 16) ? ws[lane] : 0;
        #pragma unroll
        for (int off = 1; off < 16; off <<= 1) {
            int y = __shfl_up(s, off, 64);
            if (lane >= off) s += y;
        }
        if (lane < 16) ws[lane] = s;  // inclusive wave-sum scan
    }
    __syncthreads();
    int woff = (w == 0) ? 0 : ws[w - 1];
    if (i < NN) ptr[i] = woff + (x - v);
    if (t == 1023) bsum[blockIdx.x] = ws[15];
}

// 1 block x 128: exclusive scan of the 98 block sums in place
__global__ __launch_bounds__(128) void scan_top(int* __restrict__ bsum) {
    __shared__ int wt[2];
    int t = threadIdx.x, lane = t & 63, w = t >> 6;
    int v = (t < 98) ? bsum[t] : 0;
    int x = v;
    #pragma unroll
    for (int off = 1; off < 64; off <<= 1) {
        int y = __shfl_up(x, off, 64);
        if (lane >= off) x += y;
    }
    if (lane == 63) wt[w] = x;
    __syncthreads();
    int add = (w == 1) ? wt[0] : 0;
    if (t < 98) bsum[t] = add + (x - v);
}

// finalize: global ptr, cursor copy, invd; ptr[NN] = NE (every dst in range)
__global__ __launch_bounds__(256) void scan_final(const int* __restrict__ deg,
                                                  const int* __restrict__ bsum,
                                                  int* __restrict__ ptr,
                                                  float* __restrict__ invd,
                                                  int* __restrict__ cursor) {
    int i = blockIdx.x * 256 + threadIdx.x;
    if (i < NN) {
        int p = ptr[i] + bsum[i >> 10];
        ptr[i] = p;
        cursor[i] = p;
        int d = deg[i];
        invd[i] = 1.0f / (float)(d > 1 ? d : 1);
    }
    if (blockIdx.x == 0 && threadIdx.x == 0) ptr[NN] = NE;
}

// ---------------------------------------------------------------------------
// x (fp32 [NN][128]) -> interleaved hi|lo rows (u32 [NN][128])
__global__ __launch_bounds__(256) void convert_x(const float* __restrict__ x,
                                                 unsigned* __restrict__ H) {
    int i = blockIdx.x * 256 + threadIdx.x;  // over NN*64 float2 pairs
    if (i >= NN * 64) return;
    float2 v = ((const float2*)x)[i];
    unsigned short h0, l0, h1, l1;
    split2(v.x, h0, l0);
    split2(v.y, h1, l1);
    int n = i >> 6, w = i & 63;
    H[(size_t)n * 128 + w]      = (unsigned)h0 | ((unsigned)h1 << 16);
    H[(size_t)n * 128 + 64 + w] = (unsigned)l0 | ((unsigned)l1 << 16);
}

// W ([Wl;Wr] virtual [256][128]) -> transposed hi/lo bf16 Wt[n=128][k=256]
__global__ __launch_bounds__(256) void convert_w(const float* __restrict__ Wlm,
                                                 const float* __restrict__ Wrm,
                                                 unsigned short* __restrict__ Wth,
                                                 unsigned short* __restrict__ Wtl) {
    int i = blockIdx.x * 256 + threadIdx.x;  // 128*256
    if (i >= 128 * 256) return;
    int n = i >> 8, k = i & 255;
    float v = (k < 128) ? Wlm[k * 128 + n] : Wrm[(k - 128) * 128 + n];
    unsigned short h, l;
    split2(v, h, l);
    Wth[i] = h;
    Wtl[i] = l;
}

// ---------------------------------------------------------------------------
// Mean aggregation over interleaved rows. One wave per node; lane loads one
// uint2 (words 2l,2l+1) per edge: lanes<32 cover the hi-plane, lanes>=32 the
// lo-plane. fp32 accumulate, one shfl_xor(32) to merge planes, coalesced
// 512B wave store. 8-way unrolled. No atomics.
__global__ __launch_bounds__(256) void aggregate_bf(const unsigned* __restrict__ H,
                                                    const int* __restrict__ csre,
                                                    const int* __restrict__ ptr,
                                                    const float* __restrict__ invd,
                                                    unsigned* __restrict__ A) {
    int gw = blockIdx.x * 4 + (threadIdx.x >> 6);
    int lane = threadIdx.x & 63;
    if (gw >= NN) return;
    int beg = ptr[gw], end = ptr[gw + 1];
    float s0 = 0.f, s1 = 0.f, s2 = 0.f, s3 = 0.f;
    int j = beg;
    for (; j + 8 <= end; j += 8) {
        int idx[8];
        #pragma unroll
        for (int q = 0; q < 8; ++q) idx[q] = csre[j + q];
        uint2 r[8];
        #pragma unroll
        for (int q = 0; q < 8; ++q)
            r[q] = *(const uint2*)(H + (size_t)idx[q] * 128 + lane * 2);
        #pragma unroll
        for (int q = 0; q < 8; ++q) {
            s0 += lo_f(r[q].x);
            s1 += hi_f(r[q].x);
            s2 += lo_f(r[q].y);
            s3 += hi_f(r[q].y);
        }
    }
    for (; j < end; ++j) {
        uint2 r = *(const uint2*)(H + (size_t)csre[j] * 128 + lane * 2);
        s0 += lo_f(r.x);
        s1 += hi_f(r.x);
        s2 += lo_f(r.y);
        s3 += hi_f(r.y);
    }
    // merge hi-plane (lanes<32) with lo-plane (lanes>=32) sums: lane l and
    // l^32 hold the same 4 features' partial sums
    s0 += __shfl_xor(s0, 32, 64);
    s1 += __shfl_xor(s1, 32, 64);
    s2 += __shfl_xor(s2, 32, 64);
    s3 += __shfl_xor(s3, 32, 64);
    float sc = invd[gw];
    float t0 = s0 * sc, t1 = s1 * sc, t2 = s2 * sc, t3 = s3 * sc;
    unsigned short h0, l0, h1, l1, h2, l2, h3, l3;
    split2(t0, h0, l0);
    split2(t1, h1, l1);
    split2(t2, h2, l2);
    split2(t3, h3, l3);
    unsigned w0, w1;
    if (lane < 32) {  // write hi words 2l, 2l+1
        w0 = (unsigned)h0 | ((unsigned)h1 << 16);
        w1 = (unsigned)h2 | ((unsigned)h3 << 16);
    } else {          // write lo words 2l, 2l+1 (= lo-plane of features 4(l-32)..)
        w0 = (unsigned)l0 | ((unsigned)l1 << 16);
        w1 = (unsigned)l2 | ((unsigned)l3 << 16);
    }
    *(uint2*)(A + (size_t)gw * 128 + lane * 2) = make_uint2(w0, w1);
}

// ---------------------------------------------------------------------------
// MFMA GEMM with split-bf16 (3-term): C[64 x 128] = [A0|A1] @ Wt^T + bias
// v2: LDS-staged epilogue (each wave builds its 16-row x 512B output tile in
// a private LDS slice, then flushes with 8 coalesced uint4 stores/lane-group)
// -- removes the 2B-scattered-store write amplification (WRITE 81->52MB) and
// the 64-store-instruction serialization. B hi-fragments preloaded per
// col-tile so the 24-MFMA chain hides the bl loads.
// Row stride in LDS = 544B (8-bank shift between lh groups: ds writes land
// 2 lanes/bank = conflict-free per m136).
// mode 0: relu, write interleaved hi|lo rows. mode 1: no relu, write fp32.
__global__ __launch_bounds__(256) void gemm_mfma(const unsigned* __restrict__ A0,
                                                 const unsigned* __restrict__ A1,
                                                 const unsigned short* __restrict__ Wh,
                                                 const unsigned short* __restrict__ Wl_,
                                                 const float* __restrict__ bias,
                                                 unsigned* __restrict__ O,
                                                 float* __restrict__ Of,
                                                 int mode) {
    __shared__ uint4 smem[4][16][34];  // 4 waves x 16 rows x 544B
    int t = threadIdx.x;
    int w = t >> 6, l = t & 63;
    int lr = l & 15, lh = l >> 4;
    int m0 = blockIdx.x * 64 + w * 16;
    int ra = m0 + lr;
    if (ra >= NN) ra = NN - 1;
    const char* pa0 = (const char*)(A0 + (size_t)ra * 128);
    const char* pa1 = (const char*)(A1 + (size_t)ra * 128);
    bf16x8 ah[8], al[8];
    #pragma unroll
    for (int s = 0; s < 4; ++s) {
        int off = s * 64 + lh * 16;
        ah[s]     = *(const bf16x8*)(pa0 + off);
        al[s]     = *(const bf16x8*)(pa0 + 256 + off);
        ah[s + 4] = *(const bf16x8*)(pa1 + off);
        al[s + 4] = *(const bf16x8*)(pa1 + 256 + off);
    }
    float bv[8];
    #pragma unroll
    for (int ct = 0; ct < 8; ++ct) bv[ct] = bias[ct * 16 + lr];

    #pragma unroll
    for (int ct = 0; ct < 8; ++ct) {
        int colr = ct * 16 + lr;
        const char* pbh = (const char*)Wh + (size_t)colr * 512;
        const char* pbl = (const char*)Wl_ + (size_t)colr * 512;
        bf16x8 bh[8];
        #pragma unroll
        for (int s = 0; s < 8; ++s) bh[s] = *(const bf16x8*)(pbh + s * 64 + lh * 16);
        f32x4 acc = {0.f, 0.f, 0.f, 0.f};
        #pragma unroll
        for (int s = 0; s < 8; ++s) {
            bf16x8 bl = *(const bf16x8*)(pbl + s * 64 + lh * 16);
            acc = __builtin_amdgcn_mfma_f32_16x16x32_bf16(ah[s], bh[s], acc, 0, 0, 0);
            acc = __builtin_amdgcn_mfma_f32_16x16x32_bf16(ah[s], bl, acc, 0, 0, 0);
            acc = __builtin_amdgcn_mfma_f32_16x16x32_bf16(al[s], bh[s], acc, 0, 0, 0);
        }
        // stage this col-tile into the wave's LDS output tile
        #pragma unroll
        for (int r = 0; r < 4; ++r) {
            int rl = lh * 4 + r;
            char* rb = (char*)&smem[w][rl][0];
            float v = acc[r] + bv[ct];
            if (mode == 0) {
                v = fmaxf(v, 0.f);
                unsigned short hh, ll;
                split2(v, hh, ll);
                *(unsigned short*)(rb + colr * 2) = hh;
                *(unsigned short*)(rb + 256 + colr * 2) = ll;
            } else {
                *(float*)(rb + colr * 4) = v;
            }
        }
    }
    // flush: 8 coalesced uint4 stores per lane (wave-private tile, no barrier;
    // compiler inserts lgkmcnt for same-wave LDS dependencies)
    #pragma unroll
    for (int i = 0; i < 8; ++i) {
        int idx = l + 64 * i;          // 0..511 -> 16 rows x 32 chunks
        int rl = idx >> 5;
        int co = (idx & 31) * 16;
        int rg = m0 + rl;
        if (rg < NN) {
            uint4 v = *(const uint4*)((const char*)&smem[w][rl][0] + co);
            if (mode == 0) *(uint4*)((char*)O + (size_t)rg * 512 + co) = v;
            else           *(uint4*)((char*)Of + (size_t)rg * 512 + co) = v;
        }
    }
}

// ---------------------------------------------------------------------------
extern "C" void kernel_launch(void* const* d_in, const int* in_sizes, int n_in,
                              void* d_out, int out_size, void* d_ws, size_t ws_size,
                              hipStream_t stream) {
    const float* x   = (const float*)d_in[0];
    const int*   ei  = (const int*)d_in[1];
    const float* Wl0 = (const float*)d_in[2];
    const float* bl0 = (const float*)d_in[3];
    const float* Wr0 = (const float*)d_in[4];
    const float* Wl1 = (const float*)d_in[5];
    const float* bl1 = (const float*)d_in[6];
    const float* Wr1 = (const float*)d_in[7];
    const float* Wl2 = (const float*)d_in[8];
    const float* bl2 = (const float*)d_in[9];
    const float* Wr2 = (const float*)d_in[10];
    float* out = (float*)d_out;

    char* p = (char*)d_ws;
    auto alloc = [&](size_t bytes) {
        char* q = p;
        p += (bytes + 255) & ~(size_t)255;
        return q;
    };
    int*   deg    = (int*)alloc((size_t)NN * 4);
    int*   ptr    = (int*)alloc((size_t)(NN + 1) * 4);
    int*   cursor = (int*)alloc((size_t)NN * 4);
    int*   csre   = (int*)alloc((size_t)NE * 4);
    float* invd   = (float*)alloc((size_t)NN * 4);
    int*   flag   = (int*)alloc(256);
    int*   bsum   = (int*)alloc(128 * 4);
    unsigned short* Wth0 = (unsigned short*)alloc(128 * 256 * 2);
    unsigned short* Wtl0 = (unsigned short*)alloc(128 * 256 * 2);
    unsigned short* Wth1 = (unsigned short*)alloc(128 * 256 * 2);
    unsigned short* Wtl1 = (unsigned short*)alloc(128 * 256 * 2);
    unsigned short* Wth2 = (unsigned short*)alloc(128 * 256 * 2);
    unsigned short* Wtl2 = (unsigned short*)alloc(128 * 256 * 2);
    unsigned* xH   = (unsigned*)alloc((size_t)NN * 128 * 4);  // also h2
    unsigned* aggH = (unsigned*)alloc((size_t)NN * 128 * 4);
    // h1 lives in d_out's bytes (51.2 MB = NN*512B exactly; dead before the
    // final fp32 write)
    unsigned* h1H = (unsigned*)d_out;

    // ---- CSR build (structure shared by all 3 layers)
    hipMemsetAsync(deg, 0, (size_t)NN * 4, stream);
    detect_kernel<<<1, 256, 0, stream>>>(ei, flag);
    count_deg_x<<<8 * NSLICE, 256, 0, stream>>>(ei, flag, deg);
    scan_part<<<(NN + 1023) / 1024, 1024, 0, stream>>>(deg, ptr, bsum);
    scan_top<<<1, 128, 0, stream>>>(bsum);
    scan_final<<<(NN + 255) / 256, 256, 0, stream>>>(deg, bsum, ptr, invd, cursor);
    fill_csr_x<<<8 * NSLICE, 256, 0, stream>>>(ei, flag, cursor, csre);

    // ---- operand conversion
    convert_x<<<(NN * 64 + 255) / 256, 256, 0, stream>>>(x, xH);
    convert_w<<<128, 256, 0, stream>>>(Wl0, Wr0, Wth0, Wtl0);
    convert_w<<<128, 256, 0, stream>>>(Wl1, Wr1, Wth1, Wtl1);
    convert_w<<<128, 256, 0, stream>>>(Wl2, Wr2, Wth2, Wtl2);

    dim3 blk(256);
    dim3 gAgg(NN / 4);
    dim3 gGemm((NN + 63) / 64);

    // ---- layer 0: x -> h1 (relu), h1 stored in d_out bytes
    aggregate_bf<<<gAgg, blk, 0, stream>>>(xH, csre, ptr, invd, aggH);
    gemm_mfma<<<gGemm, blk, 0, stream>>>(aggH, xH, Wth0, Wtl0, bl0, h1H, nullptr, 0);
    // ---- layer 1: h1 -> h2 (relu), h2 reuses xH (dead after layer-0 gemm)
    aggregate_bf<<<gAgg, blk, 0, stream>>>(h1H, csre, ptr, invd, aggH);
    gemm_mfma<<<gGemm, blk, 0, stream>>>(aggH, h1H, Wth1, Wtl1, bl1, xH, nullptr, 0);
    // ---- layer 2: h2 -> out (fp32, no relu); h1H (d_out bytes) dead by now
    aggregate_bf<<<gAgg, blk, 0, stream>>>(xH, csre, ptr, invd, aggH);
    gemm_mfma<<<gGemm, blk, 0, stream>>>(aggH, xH, Wth2, Wtl2, bl2, nullptr, out, 1);
}